// Round 11
// baseline (123.551 us; speedup 1.0000x reference)
//
#include <hip/hip_runtime.h>
#include <math.h>

#define NUM_E   100000
#define HIDDEN  64
#define BATCH   32
#define GAMMA_F 12.0f
#define EMB_RANGE_F 0.21875f                       // (12+2)/64
#define INV_TWO_EMB (1.0f / (2.0f * EMB_RANGE_F))  // rev = r * this = phase/(2pi)

typedef float v4f __attribute__((ext_vector_type(4)));
typedef float v2f __attribute__((ext_vector_type(2)));

// ---- packed-f32 VALU (VOP3P), byte-exact R6/R9/R10 helpers (all PASSED) ----
static __device__ __forceinline__ v2f pk_sub(v2f a, v2f b) {
    v2f d;
    asm("v_pk_add_f32 %0, %1, %2 neg_lo:[0,1] neg_hi:[0,1]"
        : "=v"(d) : "v"(a), "v"(b));
    return d;
}
static __device__ __forceinline__ v2f pk_mul(v2f a, v2f b) {
    v2f d;
    asm("v_pk_mul_f32 %0, %1, %2" : "=v"(d) : "v"(a), "v"(b));
    return d;
}
static __device__ __forceinline__ v2f pk_fma(v2f a, v2f b, v2f c) {
    v2f d;
    asm("v_pk_fma_f32 %0, %1, %2, %3" : "=v"(d) : "v"(a), "v"(b), "v"(c));
    return d;
}
// scalar-accumulating sq2 (verified R6/R9/R10). The sq2v/pk_add variant is
// the common element of the two failing rounds (R7/R8, identical absmax
// 2.75 across different data paths) — do not reintroduce.
static __device__ __forceinline__ float sq2(v2f dx, v2f dy) {
    v2f sq = pk_fma(dy, dy, pk_mul(dx, dx));
    return __builtin_amdgcn_sqrtf(sq.x) + __builtin_amdgcn_sqrtf(sq.y);
}
static __device__ __forceinline__ v2f lo2(v4f v) { return __builtin_shufflevector(v, v, 0, 1); }
static __device__ __forceinline__ v2f hi2(v4f v) { return __builtin_shufflevector(v, v, 2, 3); }

// cross-lane add via DPP quad_perm (VALU pipe), R6-verified
template <int CTRL>
static __device__ __forceinline__ float dpp_xor_add(float x) {
    int y = __builtin_amdgcn_update_dpp(0, __float_as_int(x), CTRL, 0xF, 0xF, true);
    return x + __int_as_float(y);
}

// Kernel A: re_rot/im_rot for all (b,d) into workspace (R6 verbatim).
__global__ void rotate_phase_kernel(const int* __restrict__ facts,
                                    const float* __restrict__ ent,
                                    const float* __restrict__ rel,
                                    float* __restrict__ rot) {
    int p = blockIdx.x * blockDim.x + threadIdx.x;   // 0..2047
    if (p >= BATCH * HIDDEN) return;
    int b = p >> 6;
    int d = p & 63;
    int f0 = facts[b * 3 + 0];
    int f1 = facts[b * 3 + 1];
    float hre = ent[(size_t)f0 * 128 + d];
    float him = ent[(size_t)f0 * 128 + 64 + d];
    float r   = rel[(size_t)f1 * 64 + d];
    float rev = r * INV_TWO_EMB;                 // phase/(2pi)
    float s = __builtin_amdgcn_sinf(rev);
    float c = __builtin_amdgcn_cosf(rev);
    rot[p]                  = hre * c - him * s;
    rot[BATCH * HIDDEN + p] = hre * s + him * c;
}

// Kernel B (R11) = R6's verified compute/reduce/transpose with ent moved
// from the DS pipe to the idle VMEM pipe:
//  - NO LDS staging: each lane global-loads its own 8-dim re/im slices
//    (4 global_load_dwordx4 per entity; 8 lanes share each 32B segment;
//    one 128B line per row, row read once device-wide). Deletes ~1700
//    CU-cyc/block of DS work (R6's co-dominant pipe at VALUBusy=62%).
//    Addressing identical to R8, whose failure is attributed to sq2v
//    (R7+R8 failed with IDENTICAL absmax on different data paths).
//  - scratch stride 40 (verified R9/R10): read bank (8el+bA)%32 <=2-way.
//  - grid 3125 blocks (R6-best; R9/R10 big-block variants regressed).
//  - two kernels (R9/R10 fusion regressed: compiler won't hold RR/RI).
__global__ __launch_bounds__(256, 4) void rotate_dist_kernel(
        const float* __restrict__ ent,
        const float* __restrict__ rot,
        float* __restrict__ out) {
    __shared__ float s_scr[4][4 * 40];     // per-wave transpose scratch only

    const int t    = threadIdx.x;
    const int lane = t & 63;
    const int wv   = t >> 6;
    const int bg   = lane >> 3;            // batches 4bg..4bg+3
    const int dg   = lane & 7;             // dims 8dg..8dg+7
    const int e0   = blockIdx.x * 32 + wv * 8;

    // rot slice -> registers (R6 verbatim; compiler may reload per grp from
    // the L2-hot 16KB rot buffer — measured-cheap in R6)
    v2f RR[4][4], RI[4][4];
#pragma unroll
    for (int kb = 0; kb < 4; ++kb) {
        const v4f* pr = (const v4f*)(rot + (bg * 4 + kb) * 64 + dg * 8);
        const v4f* pi = (const v4f*)(rot + 2048 + (bg * 4 + kb) * 64 + dg * 8);
        v4f a = pr[0], b = pr[1], c = pi[0], d = pi[1];
        RR[kb][0] = lo2(a); RR[kb][1] = hi2(a); RR[kb][2] = lo2(b); RR[kb][3] = hi2(b);
        RI[kb][0] = lo2(c); RI[kb][1] = hi2(c); RI[kb][2] = lo2(d); RI[kb][3] = hi2(d);
    }

    float* scr = s_scr[wv];

#pragma unroll 1
    for (int grp = 0; grp < 2; ++grp) {
        float p[4][4];                     // [entity i][batch kb]

#pragma unroll
        for (int i = 0; i < 4; ++i) {
            const float* gb = ent + (size_t)(e0 + grp * 4 + i) * 128 + dg * 8;
            v4f er0 = *(const v4f*)(gb);       // re dims 8dg..8dg+3
            v4f er1 = *(const v4f*)(gb + 4);   // re dims 8dg+4..8dg+7
            v4f ei0 = *(const v4f*)(gb + 64);  // im
            v4f ei1 = *(const v4f*)(gb + 68);
            v2f e2[4] = { lo2(er0), hi2(er0), lo2(er1), hi2(er1) };
            v2f i2[4] = { lo2(ei0), hi2(ei0), lo2(ei1), hi2(ei1) };
#pragma unroll
            for (int kb = 0; kb < 4; ++kb) {
                float s0 = sq2(pk_sub(RR[kb][0], e2[0]), pk_sub(RI[kb][0], i2[0]));
                float s1 = sq2(pk_sub(RR[kb][1], e2[1]), pk_sub(RI[kb][1], i2[1]));
                float s2 = sq2(pk_sub(RR[kb][2], e2[2]), pk_sub(RI[kb][2], i2[2]));
                float s3 = sq2(pk_sub(RR[kb][3], e2[3]), pk_sub(RI[kb][3], i2[3]));
                p[i][kb] = (s0 + s1) + (s2 + s3);
            }
        }

        // full reduction over dg: DPP xor1,xor2 + shfl_xor(4) (verified)
#pragma unroll
        for (int i = 0; i < 4; ++i)
#pragma unroll
            for (int kb = 0; kb < 4; ++kb) {
                float v = p[i][kb];
                v = dpp_xor_add<0xB1>(v);      // quad_perm [1,0,3,2]
                v = dpp_xor_add<0x4E>(v);      // quad_perm [2,3,0,1]
                v += __shfl_xor(v, 4, 64);
                p[i][kb] = GAMMA_F - v;        // all lanes hold final
            }

        // transpose via scratch (stride 40, verified R9/R10), coalesced stores
        if (dg < 4) {
#pragma unroll
            for (int i = 0; i < 4; ++i) {
                float val = (dg == 0) ? p[i][0] : (dg == 1) ? p[i][1]
                          : (dg == 2) ? p[i][2] : p[i][3];
                scr[i * 40 + bg * 4 + dg] = val;
            }
        }
#pragma unroll
        for (int j = 0; j < 2; ++j) {
            const int b  = (lane >> 2) + 16 * j;
            const int el = lane & 3;
            float v = scr[el * 40 + b];
            out[(size_t)b * NUM_E + e0 + grp * 4 + el] = v;
        }
    }
}

extern "C" void kernel_launch(void* const* d_in, const int* in_sizes, int n_in,
                              void* d_out, int out_size, void* d_ws, size_t ws_size,
                              hipStream_t stream) {
    const int*   facts = (const int*)d_in[0];
    const float* ent   = (const float*)d_in[1];
    const float* rel   = (const float*)d_in[2];
    float*       out   = (float*)d_out;
    float*       rot   = (float*)d_ws;            // 4096 floats = 16 KB

    rotate_phase_kernel<<<dim3((BATCH * HIDDEN + 255) / 256), dim3(256), 0, stream>>>(
        facts, ent, rel, rot);

    // 3125 blocks x 4 waves x 8 entities = 100000 exactly
    rotate_dist_kernel<<<dim3(NUM_E / 32), dim3(256), 0, stream>>>(
        ent, rot, out);
}